// Round 16
// baseline (294.928 us; speedup 1.0000x reference)
//
#include <hip/hip_runtime.h>
#include <hip/hip_bf16.h>

// ---------------------------------------------------------------------------
// Problem: N=2, S=2048, C=1024, A=1024, H=16, d=64, MAXLEN=2048
// Outputs: y [2,2048,1024] fp32  then  attn [2,16,2048,2048] fp32 (concat flat)
// ---------------------------------------------------------------------------

typedef __attribute__((ext_vector_type(8))) short s16x8;   // 8 x bf16 bits (4 VGPR)
typedef __attribute__((ext_vector_type(4))) float f32x4;   // MFMA acc / nt stores

#define NEGV (-1e30f)
#define K1   0.1803368801111244f   /* 0.125 * log2(e) */

static __device__ __forceinline__ short f2bf(float f) {
  unsigned u = __float_as_uint(f);
  unsigned r = (u + 0x7fffu + ((u >> 16) & 1u)) >> 16;
  return (short)r;
}
static __device__ __forceinline__ float bf2f(short s) {
  return __uint_as_float(((unsigned)(unsigned short)s) << 16);
}

// async global->LDS, 16B per lane; lds dest wave-uniform (HW adds lane*16)
static __device__ __forceinline__ void gload_lds16(const void* g, void* l) {
  __builtin_amdgcn_global_load_lds(
      (const __attribute__((address_space(1))) void*)g,
      (__attribute__((address_space(3))) void*)l, 16, 0, 0);
}

// barrier that does NOT drain vmcnt: attn global stores stay in flight.
// staging is reg->ds_write, so lgkmcnt(0) suffices for LDS visibility.
static __device__ __forceinline__ void block_sync_lds() {
  __builtin_amdgcn_sched_barrier(0);
  asm volatile("s_waitcnt lgkmcnt(0)" ::: "memory");
  __builtin_amdgcn_s_barrier();
  __builtin_amdgcn_sched_barrier(0);
}

// nontemporal 16B store: no L2 allocation for streaming output (nt flag).
// f32x4 is a clang ext_vector -> accepted by the builtin (float4 is not).
static __device__ __forceinline__ void nt_store4(float* p, f32x4 v) {
  __builtin_nontemporal_store(v, (f32x4*)p);
}

// ---------------- fused preprocessing (1 launch replaces 5) ----------------
// blocks 0..2047        : x fp32 -> xb bf16 (8 elems/thread)
// blocks 2048..5119     : W_qkv [1024][3072] -> WqkvT [3072][1024] bf16
// blocks 5120..6143     : W_out [1024][1024] -> WoutT [1024][1024] bf16
// blocks 6144..6271     : rel_table -> tabS [16][2048] bf16 *log2e
// blocks 6272..6287     : mask -> u64 bitwords
__global__ __launch_bounds__(256) void prep_all(
    const float* __restrict__ x, short* __restrict__ xb,
    const float* __restrict__ W_qkv, short* __restrict__ WqkvT,
    const float* __restrict__ W_out, short* __restrict__ WoutT,
    const float* __restrict__ rel_table, short* __restrict__ tabS,
    const int* __restrict__ mask, unsigned long long* __restrict__ mkb)
{
  __shared__ float tile[32][33];
  int b = blockIdx.x, tid = threadIdx.x;
  if (b < 2048) {
    int i = (b * 256 + tid) * 8;
    float4 a = *(const float4*)&x[i];
    float4 bb = *(const float4*)&x[i + 4];
    s16x8 v;
    v[0] = f2bf(a.x); v[1] = f2bf(a.y); v[2] = f2bf(a.z); v[3] = f2bf(a.w);
    v[4] = f2bf(bb.x); v[5] = f2bf(bb.y); v[6] = f2bf(bb.z); v[7] = f2bf(bb.w);
    *(s16x8*)&xb[i] = v;
  } else if (b < 6144) {
    const float* in; short* out; int R, Cc, bx, by;
    if (b < 5120) {
      int bb = b - 2048; in = W_qkv; out = WqkvT; R = 1024; Cc = 3072;
      bx = bb % 96; by = bb / 96;
    } else {
      int bb = b - 5120; in = W_out; out = WoutT; R = 1024; Cc = 1024;
      bx = bb & 31; by = bb >> 5;
    }
    int c0 = bx * 32, r0 = by * 32;
    int tx = tid & 31, ty = tid >> 5;            // (32,8) shape
    for (int i = 0; i < 32; i += 8)
      tile[ty + i][tx] = in[(size_t)(r0 + ty + i) * Cc + c0 + tx];
    __syncthreads();
    for (int i = 0; i < 32; i += 8)
      out[(size_t)(c0 + ty + i) * R + r0 + tx] = f2bf(tile[tx][ty + i]);
  } else if (b < 6272) {
    int i = (b - 6144) * 256 + tid;              // 0..32767
    int l = i >> 4, h = i & 15;
    tabS[h * 2048 + l] = f2bf(rel_table[i] * 1.4426950408889634f);
  } else {
    int g = (b - 6272) * 256 + tid;              // 0..4095
    unsigned long long bal = __ballot(mask[g] != 0);
    if ((tid & 63) == 0) mkb[g >> 6] = bal;
  }
}

// ---------------- V pre-transpose: qkv V-part -> VT[n][vcol][s] bf16 -------
__global__ void vt_transpose(const short* __restrict__ qkv, short* __restrict__ vt) {
  __shared__ short tile[32][33];
  int nn = blockIdx.z;
  int c0 = blockIdx.y * 32;                        // v-col (= h*64+dd)
  int r0 = blockIdx.x * 32;                        // s
  int tx = threadIdx.x, ty = threadIdx.y;          // block (32,8)
  for (int i = 0; i < 32; i += 8)
    tile[ty + i][tx] = qkv[(size_t)(nn * 2048 + r0 + ty + i) * 3072 + 2048 + c0 + tx];
  __syncthreads();
  for (int i = 0; i < 32; i += 8)
    vt[(size_t)(nn * 1024 + c0 + ty + i) * 2048 + r0 + tx] = tile[tx][ty + i];
}

// ---------------- bf16 MFMA GEMM (m97 structure): C = A * BT^T -------------
template<bool OUT_F32>
__global__ __launch_bounds__(256) void gemm_bt(
    const short* __restrict__ A, const short* __restrict__ BT,
    void* __restrict__ Cout, int M, int Nn, int K)
{
  __shared__ short As[128 * 64];
  __shared__ short Bs[128 * 64];
  int bn = blockIdx.x, bm = blockIdx.y;
  int tid = threadIdx.x, wave = tid >> 6, lane = tid & 63;
  int wr = wave >> 1, wc = wave & 1;
  int lc = lane & 15, lg = lane >> 4;
  f32x4 acc[4][4];
  for (int i = 0; i < 4; ++i)
    for (int j = 0; j < 4; ++j) acc[i][j] = (f32x4){0.f, 0.f, 0.f, 0.f};
  const short* Abase = A  + (size_t)(bm * 128) * K;
  const short* Bbase = BT + (size_t)(bn * 128) * K;
  int srow = lane >> 3;
  int scol = (lane & 7) * 8;
  for (int k0 = 0; k0 < K; k0 += 64) {
    __syncthreads();
    #pragma unroll
    for (int it = 0; it < 4; ++it) {
      int chunk = it * 4 + wave;
      int grow = chunk * 8 + srow;
      gload_lds16(&Abase[(size_t)grow * K + k0 + scol], &As[chunk * 512]);
      gload_lds16(&Bbase[(size_t)grow * K + k0 + scol], &Bs[chunk * 512]);
    }
    __syncthreads();
    #pragma unroll
    for (int ks = 0; ks < 2; ++ks) {
      s16x8 af[4], bfr[4];
      #pragma unroll
      for (int mi = 0; mi < 4; ++mi)
        af[mi] = *(const s16x8*)&As[(wr * 64 + mi * 16 + lc) * 64 + ks * 32 + lg * 8];
      #pragma unroll
      for (int ni = 0; ni < 4; ++ni)
        bfr[ni] = *(const s16x8*)&Bs[(wc * 64 + ni * 16 + lc) * 64 + ks * 32 + lg * 8];
      #pragma unroll
      for (int mi = 0; mi < 4; ++mi)
        #pragma unroll
        for (int ni = 0; ni < 4; ++ni)
          acc[mi][ni] = __builtin_amdgcn_mfma_f32_16x16x32_bf16(af[mi], bfr[ni], acc[mi][ni], 0, 0, 0);
    }
  }
  int row0 = bm * 128 + wr * 64, col0 = bn * 128 + wc * 64;
  for (int mi = 0; mi < 4; ++mi)
    for (int ni = 0; ni < 4; ++ni)
      for (int r = 0; r < 4; ++r) {
        int row = row0 + mi * 16 + lg * 4 + r;
        int col = col0 + ni * 16 + lc;
        if constexpr (OUT_F32)
          ((float*)Cout)[(size_t)row * Nn + col] = acc[mi][ni][r];
        else
          ((short*)Cout)[(size_t)row * Nn + col] = f2bf(acc[mi][ni][r]);
      }
}

// ---------------- GEMM variant: 128x64 tile (for y = y_ws @ WoutT) ---------
__global__ __launch_bounds__(256) void gemm_bt64(
    const short* __restrict__ A, const short* __restrict__ BT,
    float* __restrict__ Cout, int M, int Nn, int K)
{
  __shared__ short As[128 * 64];
  __shared__ short Bs[64 * 64];
  int bn = blockIdx.x, bm = blockIdx.y;
  int tid = threadIdx.x, wave = tid >> 6, lane = tid & 63;
  int wr = wave >> 1, wc = wave & 1;
  int lc = lane & 15, lg = lane >> 4;
  f32x4 acc[4][2];
  for (int i = 0; i < 4; ++i)
    for (int j = 0; j < 2; ++j) acc[i][j] = (f32x4){0.f, 0.f, 0.f, 0.f};
  const short* Abase = A  + (size_t)(bm * 128) * K;
  const short* Bbase = BT + (size_t)(bn * 64) * K;
  int srow = lane >> 3;
  int scol = (lane & 7) * 8;
  for (int k0 = 0; k0 < K; k0 += 64) {
    __syncthreads();
    #pragma unroll
    for (int it = 0; it < 4; ++it) {
      int chunk = it * 4 + wave;
      gload_lds16(&Abase[(size_t)(chunk * 8 + srow) * K + k0 + scol], &As[chunk * 512]);
    }
    #pragma unroll
    for (int it = 0; it < 2; ++it) {
      int chunk = it * 4 + wave;
      gload_lds16(&Bbase[(size_t)(chunk * 8 + srow) * K + k0 + scol], &Bs[chunk * 512]);
    }
    __syncthreads();
    #pragma unroll
    for (int ks = 0; ks < 2; ++ks) {
      s16x8 af[4], bfr[2];
      #pragma unroll
      for (int mi = 0; mi < 4; ++mi)
        af[mi] = *(const s16x8*)&As[(wr * 64 + mi * 16 + lc) * 64 + ks * 32 + lg * 8];
      #pragma unroll
      for (int ni = 0; ni < 2; ++ni)
        bfr[ni] = *(const s16x8*)&Bs[(wc * 32 + ni * 16 + lc) * 64 + ks * 32 + lg * 8];
      #pragma unroll
      for (int mi = 0; mi < 4; ++mi)
        #pragma unroll
        for (int ni = 0; ni < 2; ++ni)
          acc[mi][ni] = __builtin_amdgcn_mfma_f32_16x16x32_bf16(af[mi], bfr[ni], acc[mi][ni], 0, 0, 0);
    }
  }
  int row0 = bm * 128 + wr * 64, col0 = bn * 64 + wc * 32;
  for (int mi = 0; mi < 4; ++mi)
    for (int ni = 0; ni < 2; ++ni)
      for (int r = 0; r < 4; ++r)
        __builtin_nontemporal_store(acc[mi][ni][r],   // scalar float: legal
            &Cout[(size_t)(row0 + mi * 16 + lg * 4 + r) * Nn + col0 + ni * 16 + lc]);
}

// ---------------- fused attention (R15 structure, occupancy-5 package) -----
// grid 1024 x 256 (4 waves); slot-balanced qt map. LDS diet: bf16 rtab ->
// 31.9 KB total -> 5 blocks/CU (20 waves/CU, was 16). launch_bounds(256,5)
// caps VGPR at 102; V frags loaded inside PV ni-loop (8 live, not 32) to fit.
// Pass 1 = uniform 32 rounds (sums or nt zero-fill); pass 2 = emit + PV.
// All attn_out stores nontemporal; lgkm-only barriers keep stores in flight.
__global__ __launch_bounds__(256, 5) void attn_fused(
    const short* __restrict__ qkv,     // [4096][3072] bf16
    const short* __restrict__ vt,      // [2][1024][2048] bf16 (V^T)
    const unsigned long long* __restrict__ mkb,  // [2][32]
    const short* __restrict__ tabS,    // [16][2048] bf16, *log2e
    float* __restrict__ attn_out,      // [2][16][2048][2048]
    short* __restrict__ y_ws)          // [4096][1024] bf16
{
  int bid = blockIdx.x;
  int slot = bid >> 8, r_ = bid & 255;
  int nh = r_ & 31, i_ = r_ >> 5;
  int n = nh >> 4, h = nh & 15;
  int qt;                              // slot table: sums to 62 per (i_, nh)
  switch (slot) {
    case 0:  qt = i_;      break;      // 0..7
    case 1:  qt = 15 - i_; break;      // 15..8
    case 2:  qt = 16 + i_; break;      // 16..23
    default: qt = 31 - i_; break;      // 31..24
  }

  int tid = threadIdx.x, wave = tid >> 6, lane = tid & 63;
  int lc = lane & 15, lg = lane >> 4, lg4 = lg * 4;

  __shared__ short QPs[64][72];        // Q then P (wave-local 16-row strips)
  __shared__ short Ks[2][64][72];
  __shared__ short rtabS[2048 + 64];   // reversed bias (bf16,*log2e); +64 slack

  for (int ii = tid; ii < 2048; ii += 256) rtabS[2047 - ii] = tabS[h * 2048 + ii];

  int sr = tid >> 3, sc = (tid & 7) * 8;           // staging rows sr, sr+32
  const short* kbase0 = qkv + (size_t)(n * 2048) * 3072 + 1024 + h * 64;
  const short* vtbase = vt + (size_t)(n * 1024 + h * 64) * 2048;
  const unsigned long long* mw = mkb + n * 32;
  float* aout = attn_out + (size_t)(n * 16 + h) * 2048 * 2048;

  // stage Q + K0
  const short* qbase = qkv + (size_t)(n * 2048 + qt * 64) * 3072 + h * 64;
  *(s16x8*)&QPs[sr][sc]        = *(const s16x8*)&qbase[(size_t)sr * 3072 + sc];
  *(s16x8*)&QPs[sr + 32][sc]   = *(const s16x8*)&qbase[(size_t)(sr + 32) * 3072 + sc];
  *(s16x8*)&Ks[0][sr][sc]      = *(const s16x8*)&kbase0[(size_t)sr * 3072 + sc];
  *(s16x8*)&Ks[0][sr + 32][sc] = *(const s16x8*)&kbase0[(size_t)(sr + 32) * 3072 + sc];
  __syncthreads();

  s16x8 aq[2];
  #pragma unroll
  for (int ks = 0; ks < 2; ++ks)
    aq[ks] = *(const s16x8*)&QPs[wave * 16 + lc][ks * 32 + lg * 8];
  int qrow = qt * 64 + wave * 16 + lc;
  bool qv = ((mw[qrow >> 6] >> (qrow & 63)) & 1ull) != 0;
  float l = 0.f;

  // ---- pass 1: uniform 32 rounds (compute row sums OR zero-fill) ----------
  for (int kt = 0; kt < 32; ++kt) {
    int cur = kt & 1;
    s16x8 kn0, kn1;
    bool pf = (kt + 1 <= qt);
    if (pf) {
      const short* kb = kbase0 + (size_t)(kt + 1) * 64 * 3072;
      kn0 = *(const s16x8*)&kb[(size_t)sr * 3072 + sc];
      kn1 = *(const s16x8*)&kb[(size_t)(sr + 32) * 3072 + sc];
    }
    if (kt <= qt) {
      int lim = qrow - kt * 64;
      unsigned long long w = mw[kt];
      f32x4 c[4];
      __builtin_amdgcn_s_setprio(1);
      #pragma unroll
      for (int ni = 0; ni < 4; ++ni) {
        c[ni] = (f32x4){0.f, 0.f, 0.f, 0.f};
        #pragma unroll
        for (int ks = 0; ks < 2; ++ks) {
          s16x8 kf = *(const s16x8*)&Ks[cur][ni * 16 + lc][ks * 32 + lg * 8];
          c[ni] = __builtin_amdgcn_mfma_f32_16x16x32_bf16(kf, aq[ks], c[ni], 0, 0, 0);
        }
      }
      __builtin_amdgcn_s_setprio(0);
      if (kt < qt) {                   // interior: no causal compare needed
        #pragma unroll
        for (int ni = 0; ni < 4; ++ni) {
          unsigned nib = (unsigned)(w >> (ni * 16 + lg4));
          int j0 = 2047 - lim + ni * 16 + lg4;
          #pragma unroll
          for (int r = 0; r < 4; ++r) {
            float v = ((nib >> r) & 1u) ? fmaf(c[ni][r], K1, bf2f(rtabS[j0 + r])) : NEGV;
            l += exp2f(v);
          }
        }
      } else {                         // diagonal tile
        #pragma unroll
        for (int ni = 0; ni < 4; ++ni) {
          unsigned nib = (unsigned)(w >> (ni * 16 + lg4));
          int j0 = 2047 - lim + ni * 16 + lg4;
          #pragma unroll
          for (int r = 0; r < 4; ++r) {
            int idx = ni * 16 + lg4 + r;
            bool ok = (((nib >> r) & 1u) != 0) && (idx <= lim);
            float v = ok ? fmaf(c[ni][r], K1, bf2f(rtabS[j0 + r])) : NEGV;
            l += exp2f(v);
          }
        }
      }
    } else {
      // zero-fill this q-tile's k-tile kt (upper triangle), nontemporal
      f32x4 z4 = (f32x4){0.f, 0.f, 0.f, 0.f};
      #pragma unroll
      for (int ii = 0; ii < 4; ++ii) {
        int idx = tid + ii * 256;                  // 0..1023
        int row = idx >> 4, c16 = idx & 15;
        nt_store4(&aout[(size_t)(qt * 64 + row) * 2048 + kt * 64 + c16 * 4], z4);
      }
    }
    if (pf) {
      *(s16x8*)&Ks[cur ^ 1][sr][sc]      = kn0;
      *(s16x8*)&Ks[cur ^ 1][sr + 32][sc] = kn1;
    }
    block_sync_lds();
  }
  l += __shfl_xor(l, 16);
  l += __shfl_xor(l, 32);
  float C_ = qv ? __log2f(l) : 1.0e30f;  // invalid q-row: exp2(v-1e30) = 0

  f32x4 y[4];
  #pragma unroll
  for (int ni = 0; ni < 4; ++ni) y[ni] = (f32x4){0.f, 0.f, 0.f, 0.f};

  // re-stage K0 for pass 2 (prev barrier protects)
  *(s16x8*)&Ks[0][sr][sc]      = *(const s16x8*)&kbase0[(size_t)sr * 3072 + sc];
  *(s16x8*)&Ks[0][sr + 32][sc] = *(const s16x8*)&kbase0[(size_t)(sr + 32) * 3072 + sc];
  block_sync_lds();

  // ---- pass 2: emit normalized attn (nt f32x4) + PV (V direct from L2) ----
  for (int kt = 0; kt <= qt; ++kt) {
    int cur = kt & 1;
    s16x8 kn0, kn1;
    if (kt < qt) {
      const short* kb = kbase0 + (size_t)(kt + 1) * 64 * 3072;
      kn0 = *(const s16x8*)&kb[(size_t)sr * 3072 + sc];
      kn1 = *(const s16x8*)&kb[(size_t)(sr + 32) * 3072 + sc];
    }
    const short* vp = vtbase + (size_t)lc * 2048 + kt * 64 + lg * 8;
    unsigned long long w = mw[kt];
    int lim = qrow - kt * 64;
    f32x4 c[4];
    __builtin_amdgcn_s_setprio(1);
    #pragma unroll
    for (int ni = 0; ni < 4; ++ni) {
      c[ni] = (f32x4){0.f, 0.f, 0.f, 0.f};
      #pragma unroll
      for (int ks = 0; ks < 2; ++ks) {
        s16x8 kf = *(const s16x8*)&Ks[cur][ni * 16 + lc][ks * 32 + lg * 8];
        c[ni] = __builtin_amdgcn_mfma_f32_16x16x32_bf16(kf, aq[ks], c[ni], 0, 0, 0);
      }
    }
    __builtin_amdgcn_s_setprio(0);
    #pragma unroll
    for (int ni = 0; ni < 4; ++ni) {
      unsigned nib = (unsigned)(w >> (ni * 16 + lg4));
      int j0 = 2047 - lim + ni * 16 + lg4;
      f32x4 p4;
      if (kt < qt) {
        #pragma unroll
        for (int r = 0; r < 4; ++r) {
          float v = ((nib >> r) & 1u) ? (fmaf(c[ni][r], K1, bf2f(rtabS[j0 + r])) - C_) : -3.0e38f;
          p4[r] = exp2f(v);
        }
      } else {
        #pragma unroll
        for (int r = 0; r < 4; ++r) {
          int idx = ni * 16 + lg4 + r;
          bool ok = (((nib >> r) & 1u) != 0) && (idx <= lim);
          float v = ok ? (fmaf(c[ni][r], K1, bf2f(rtabS[j0 + r])) - C_) : -3.0e38f;
          p4[r] = exp2f(v);
        }
      }
      nt_store4(&aout[(size_t)qrow * 2048 + kt * 64 + ni * 16 + lg4], p4);
      // cheap RNA bf16 pack (values in [0,1])
      unsigned plo = ((__float_as_uint(p4[0]) + 0x8000u) >> 16) |
                     ((__float_as_uint(p4[1]) + 0x8000u) & 0xffff0000u);
      unsigned phi = ((__float_as_uint(p4[2]) + 0x8000u) >> 16) |
                     ((__float_as_uint(p4[3]) + 0x8000u) & 0xffff0000u);
      uint2 pk; pk.x = plo; pk.y = phi;
      *(uint2*)&QPs[wave * 16 + lc][ni * 16 + lg4] = pk;  // wave-local strip
    }
    asm volatile("" ::: "memory");     // forbid hoisting P reads above writes
    __builtin_amdgcn_s_setprio(1);
    #pragma unroll
    for (int ks = 0; ks < 2; ++ks) {
      s16x8 pa = *(const s16x8*)&QPs[wave * 16 + lc][ks * 32 + lg * 8];
      #pragma unroll
      for (int ni = 0; ni < 4; ++ni) {
        // V frags loaded here (8 VGPR live, not 32): fits the (256,5) cap
        s16x8 vf0 = *(const s16x8*)&vp[(size_t)(ni * 16) * 2048 + ks * 32];
        y[ni] = __builtin_amdgcn_mfma_f32_16x16x32_bf16(pa, vf0, y[ni], 0, 0, 0);
      }
    }
    __builtin_amdgcn_s_setprio(0);
    if (kt < qt) {
      *(s16x8*)&Ks[cur ^ 1][sr][sc]      = kn0;
      *(s16x8*)&Ks[cur ^ 1][sr + 32][sc] = kn1;
    }
    block_sync_lds();
  }

  // y store (padded-query rows: p forced 0 -> y 0); y_ws IS re-read -> cached
  #pragma unroll
  for (int ni = 0; ni < 4; ++ni) {
    int col = h * 64 + ni * 16 + lc;
    #pragma unroll
    for (int r = 0; r < 4; ++r) {
      size_t row = (size_t)(n * 2048 + qt * 64 + wave * 16 + lg4 + r);
      y_ws[row * 1024 + col] = f2bf(y[ni][r]);
    }
  }
}

// ---------------------------------------------------------------------------
extern "C" void kernel_launch(void* const* d_in, const int* in_sizes, int n_in,
                              void* d_out, int out_size, void* d_ws, size_t ws_size,
                              hipStream_t stream)
{
  const float* x         = (const float*)d_in[0];
  const int*   mask      = (const int*)d_in[1];
  const float* W_qkv     = (const float*)d_in[4];
  const float* W_out     = (const float*)d_in[5];
  const float* rel_table = (const float*)d_in[6];

  char* ws = (char*)d_ws;
  short*  xb     = (short*)(ws);                 //  8,388,608 B (reused as vt)
  short*  WqkvT  = (short*)(ws + 8388608);       //  6,291,456 B
  short*  WoutT  = (short*)(ws + 14680064);      //  2,097,152 B
  short*  tabS   = (short*)(ws + 16777216);      //     65,536 B
  unsigned long long* mkb = (unsigned long long*)(ws + 16908288); // 512 B
  short*  qkv    = (short*)(ws + 16908800);      // 25,165,824 B
  short*  y_ws   = (short*)(ws + 42074624);      //  8,388,608 B (ends 50,463,232)
  short*  vt     = xb;                           // V^T, written after gemm1 reads xb

  float* y_out    = (float*)d_out;
  float* attn_out = y_out + (size_t)2 * 2048 * 1024;

  prep_all<<<6288, 256, 0, stream>>>(x, xb, W_qkv, WqkvT, W_out, WoutT,
                                     rel_table, tabS, mask, mkb);

  gemm_bt<false><<<dim3(24, 32), 256, 0, stream>>>(xb, WqkvT, (void*)qkv, 4096, 3072, 1024);

  vt_transpose<<<dim3(64, 32, 2), dim3(32, 8), 0, stream>>>(qkv, vt);

  attn_fused<<<1024, 256, 0, stream>>>(qkv, vt, mkb, tabS, attn_out, y_ws);

  gemm_bt64<<<dim3(16, 32), 256, 0, stream>>>(y_ws, WoutT, y_out, 4096, 1024, 1024);
}

// Round 17
// 273.249 us; speedup vs baseline: 1.0793x; 1.0793x over previous
//
#include <hip/hip_runtime.h>
#include <hip/hip_bf16.h>

// ---------------------------------------------------------------------------
// Problem: N=2, S=2048, C=1024, A=1024, H=16, d=64, MAXLEN=2048
// Outputs: y [2,2048,1024] fp32  then  attn [2,16,2048,2048] fp32 (concat flat)
// Final kernel = R15 (best measured: 274.2 us, absmax 0.0078).
// ---------------------------------------------------------------------------

typedef __attribute__((ext_vector_type(8))) short s16x8;   // 8 x bf16 bits (4 VGPR)
typedef __attribute__((ext_vector_type(4))) float f32x4;   // MFMA acc / nt stores

#define NEGV (-1e30f)
#define K1   0.1803368801111244f   /* 0.125 * log2(e) */

static __device__ __forceinline__ short f2bf(float f) {
  unsigned u = __float_as_uint(f);
  unsigned r = (u + 0x7fffu + ((u >> 16) & 1u)) >> 16;
  return (short)r;
}

// async global->LDS, 16B per lane; lds dest wave-uniform (HW adds lane*16)
static __device__ __forceinline__ void gload_lds16(const void* g, void* l) {
  __builtin_amdgcn_global_load_lds(
      (const __attribute__((address_space(1))) void*)g,
      (__attribute__((address_space(3))) void*)l, 16, 0, 0);
}

// barrier that does NOT drain vmcnt: attn global stores stay in flight.
// staging is reg->ds_write, so lgkmcnt(0) suffices for LDS visibility.
static __device__ __forceinline__ void block_sync_lds() {
  __builtin_amdgcn_sched_barrier(0);
  asm volatile("s_waitcnt lgkmcnt(0)" ::: "memory");
  __builtin_amdgcn_s_barrier();
  __builtin_amdgcn_sched_barrier(0);
}

// nontemporal 16B store: no L2 allocation for streaming output (nt flag).
// f32x4 is a clang ext_vector -> accepted by the builtin (float4 is not).
static __device__ __forceinline__ void nt_store4(float* p, f32x4 v) {
  __builtin_nontemporal_store(v, (f32x4*)p);
}

// ---------------- fused preprocessing (1 launch replaces 5) ----------------
// blocks 0..2047        : x fp32 -> xb bf16 (8 elems/thread)
// blocks 2048..5119     : W_qkv [1024][3072] -> WqkvT [3072][1024] bf16
// blocks 5120..6143     : W_out [1024][1024] -> WoutT [1024][1024] bf16
// blocks 6144..6271     : rel_table -> tabF [16][2048] fp32 *log2e
// blocks 6272..6287     : mask -> u64 bitwords
__global__ __launch_bounds__(256) void prep_all(
    const float* __restrict__ x, short* __restrict__ xb,
    const float* __restrict__ W_qkv, short* __restrict__ WqkvT,
    const float* __restrict__ W_out, short* __restrict__ WoutT,
    const float* __restrict__ rel_table, float* __restrict__ tabF,
    const int* __restrict__ mask, unsigned long long* __restrict__ mkb)
{
  __shared__ float tile[32][33];
  int b = blockIdx.x, tid = threadIdx.x;
  if (b < 2048) {
    int i = (b * 256 + tid) * 8;
    float4 a = *(const float4*)&x[i];
    float4 bb = *(const float4*)&x[i + 4];
    s16x8 v;
    v[0] = f2bf(a.x); v[1] = f2bf(a.y); v[2] = f2bf(a.z); v[3] = f2bf(a.w);
    v[4] = f2bf(bb.x); v[5] = f2bf(bb.y); v[6] = f2bf(bb.z); v[7] = f2bf(bb.w);
    *(s16x8*)&xb[i] = v;
  } else if (b < 6144) {
    const float* in; short* out; int R, Cc, bx, by;
    if (b < 5120) {
      int bb = b - 2048; in = W_qkv; out = WqkvT; R = 1024; Cc = 3072;
      bx = bb % 96; by = bb / 96;
    } else {
      int bb = b - 5120; in = W_out; out = WoutT; R = 1024; Cc = 1024;
      bx = bb & 31; by = bb >> 5;
    }
    int c0 = bx * 32, r0 = by * 32;
    int tx = tid & 31, ty = tid >> 5;            // (32,8) shape
    for (int i = 0; i < 32; i += 8)
      tile[ty + i][tx] = in[(size_t)(r0 + ty + i) * Cc + c0 + tx];
    __syncthreads();
    for (int i = 0; i < 32; i += 8)
      out[(size_t)(c0 + ty + i) * R + r0 + tx] = f2bf(tile[tx][ty + i]);
  } else if (b < 6272) {
    int i = (b - 6144) * 256 + tid;              // 0..32767
    int l = i >> 4, h = i & 15;
    tabF[h * 2048 + l] = rel_table[i] * 1.4426950408889634f;
  } else {
    int g = (b - 6272) * 256 + tid;              // 0..4095
    unsigned long long bal = __ballot(mask[g] != 0);
    if ((tid & 63) == 0) mkb[g >> 6] = bal;
  }
}

// ---------------- V pre-transpose: qkv V-part -> VT[n][vcol][s] bf16 -------
__global__ void vt_transpose(const short* __restrict__ qkv, short* __restrict__ vt) {
  __shared__ short tile[32][33];
  int nn = blockIdx.z;
  int c0 = blockIdx.y * 32;                        // v-col (= h*64+dd)
  int r0 = blockIdx.x * 32;                        // s
  int tx = threadIdx.x, ty = threadIdx.y;          // block (32,8)
  for (int i = 0; i < 32; i += 8)
    tile[ty + i][tx] = qkv[(size_t)(nn * 2048 + r0 + ty + i) * 3072 + 2048 + c0 + tx];
  __syncthreads();
  for (int i = 0; i < 32; i += 8)
    vt[(size_t)(nn * 1024 + c0 + ty + i) * 2048 + r0 + tx] = tile[tx][ty + i];
}

// ---------------- bf16 MFMA GEMM (m97 structure): C = A * BT^T -------------
template<bool OUT_F32>
__global__ __launch_bounds__(256) void gemm_bt(
    const short* __restrict__ A, const short* __restrict__ BT,
    void* __restrict__ Cout, int M, int Nn, int K)
{
  __shared__ short As[128 * 64];
  __shared__ short Bs[128 * 64];
  int bn = blockIdx.x, bm = blockIdx.y;
  int tid = threadIdx.x, wave = tid >> 6, lane = tid & 63;
  int wr = wave >> 1, wc = wave & 1;
  int lc = lane & 15, lg = lane >> 4;
  f32x4 acc[4][4];
  for (int i = 0; i < 4; ++i)
    for (int j = 0; j < 4; ++j) acc[i][j] = (f32x4){0.f, 0.f, 0.f, 0.f};
  const short* Abase = A  + (size_t)(bm * 128) * K;
  const short* Bbase = BT + (size_t)(bn * 128) * K;
  int srow = lane >> 3;
  int scol = (lane & 7) * 8;
  for (int k0 = 0; k0 < K; k0 += 64) {
    __syncthreads();
    #pragma unroll
    for (int it = 0; it < 4; ++it) {
      int chunk = it * 4 + wave;
      int grow = chunk * 8 + srow;
      gload_lds16(&Abase[(size_t)grow * K + k0 + scol], &As[chunk * 512]);
      gload_lds16(&Bbase[(size_t)grow * K + k0 + scol], &Bs[chunk * 512]);
    }
    __syncthreads();
    #pragma unroll
    for (int ks = 0; ks < 2; ++ks) {
      s16x8 af[4], bfr[4];
      #pragma unroll
      for (int mi = 0; mi < 4; ++mi)
        af[mi] = *(const s16x8*)&As[(wr * 64 + mi * 16 + lc) * 64 + ks * 32 + lg * 8];
      #pragma unroll
      for (int ni = 0; ni < 4; ++ni)
        bfr[ni] = *(const s16x8*)&Bs[(wc * 64 + ni * 16 + lc) * 64 + ks * 32 + lg * 8];
      #pragma unroll
      for (int mi = 0; mi < 4; ++mi)
        #pragma unroll
        for (int ni = 0; ni < 4; ++ni)
          acc[mi][ni] = __builtin_amdgcn_mfma_f32_16x16x32_bf16(af[mi], bfr[ni], acc[mi][ni], 0, 0, 0);
    }
  }
  int row0 = bm * 128 + wr * 64, col0 = bn * 128 + wc * 64;
  for (int mi = 0; mi < 4; ++mi)
    for (int ni = 0; ni < 4; ++ni)
      for (int r = 0; r < 4; ++r) {
        int row = row0 + mi * 16 + lg * 4 + r;
        int col = col0 + ni * 16 + lc;
        if constexpr (OUT_F32)
          ((float*)Cout)[(size_t)row * Nn + col] = acc[mi][ni][r];
        else
          ((short*)Cout)[(size_t)row * Nn + col] = f2bf(acc[mi][ni][r]);
      }
}

// ---------------- GEMM variant: 128x64 tile (for y = y_ws @ WoutT) ---------
__global__ __launch_bounds__(256) void gemm_bt64(
    const short* __restrict__ A, const short* __restrict__ BT,
    float* __restrict__ Cout, int M, int Nn, int K)
{
  __shared__ short As[128 * 64];
  __shared__ short Bs[64 * 64];
  int bn = blockIdx.x, bm = blockIdx.y;
  int tid = threadIdx.x, wave = tid >> 6, lane = tid & 63;
  int wr = wave >> 1, wc = wave & 1;
  int lc = lane & 15, lg = lane >> 4;
  f32x4 acc[4][2];
  for (int i = 0; i < 4; ++i)
    for (int j = 0; j < 2; ++j) acc[i][j] = (f32x4){0.f, 0.f, 0.f, 0.f};
  const short* Abase = A  + (size_t)(bm * 128) * K;
  const short* Bbase = BT + (size_t)(bn * 64) * K;
  int srow = lane >> 3;
  int scol = (lane & 7) * 8;
  for (int k0 = 0; k0 < K; k0 += 64) {
    __syncthreads();
    #pragma unroll
    for (int it = 0; it < 4; ++it) {
      int chunk = it * 4 + wave;
      gload_lds16(&Abase[(size_t)(chunk * 8 + srow) * K + k0 + scol], &As[chunk * 512]);
    }
    #pragma unroll
    for (int it = 0; it < 2; ++it) {
      int chunk = it * 4 + wave;
      gload_lds16(&Bbase[(size_t)(chunk * 8 + srow) * K + k0 + scol], &Bs[chunk * 512]);
    }
    __syncthreads();
    #pragma unroll
    for (int ks = 0; ks < 2; ++ks) {
      s16x8 af[4], bfr[2];
      #pragma unroll
      for (int mi = 0; mi < 4; ++mi)
        af[mi] = *(const s16x8*)&As[(wr * 64 + mi * 16 + lc) * 64 + ks * 32 + lg * 8];
      #pragma unroll
      for (int ni = 0; ni < 2; ++ni)
        bfr[ni] = *(const s16x8*)&Bs[(wc * 32 + ni * 16 + lc) * 64 + ks * 32 + lg * 8];
      #pragma unroll
      for (int mi = 0; mi < 4; ++mi)
        #pragma unroll
        for (int ni = 0; ni < 2; ++ni)
          acc[mi][ni] = __builtin_amdgcn_mfma_f32_16x16x32_bf16(af[mi], bfr[ni], acc[mi][ni], 0, 0, 0);
    }
  }
  int row0 = bm * 128 + wr * 64, col0 = bn * 64 + wc * 32;
  for (int mi = 0; mi < 4; ++mi)
    for (int ni = 0; ni < 2; ++ni)
      for (int r = 0; r < 4; ++r)
        __builtin_nontemporal_store(acc[mi][ni][r],   // scalar float: legal
            &Cout[(size_t)(row0 + mi * 16 + lg * 4 + r) * Nn + col0 + ni * 16 + lc]);
}

// ---------------- fused attention (R10 structure + nontemporal stores) -----
// grid 1024 x 256 (4 waves). bid -> slot=bid>>8, r=bid&255, nh=r&31 (bid%8 =
// nh%8 XCD affinity), i=r>>5. qt by slot: {i, 15-i, 16+i, 31-i} -> the 4
// blocks sharing a CU (bid, bid+256, ...) have qt sums = 62 (balance), and
// 4 independent blocks/CU drift in phase (store/compute interleave).
// Pass 1 = UNIFORM 32 rounds: kt<=qt computes row sums; kt>qt writes this
// q-tile's upper-triangle zeros. Pass 2 = qt+1 rounds: emit + PV, V direct
// from L2. ALL attn_out stores nontemporal: 537MB streams without evicting
// the K/V L2 working set (attn_out is never re-read).
__global__ __launch_bounds__(256, 4) void attn_fused(
    const short* __restrict__ qkv,     // [4096][3072] bf16
    const short* __restrict__ vt,      // [2][1024][2048] bf16 (V^T)
    const unsigned long long* __restrict__ mkb,  // [2][32]
    const float* __restrict__ tabF,    // [16][2048] fp32, *log2e
    float* __restrict__ attn_out,      // [2][16][2048][2048]
    short* __restrict__ y_ws)          // [4096][1024] bf16
{
  int bid = blockIdx.x;
  int slot = bid >> 8, r_ = bid & 255;
  int nh = r_ & 31, i_ = r_ >> 5;
  int n = nh >> 4, h = nh & 15;
  int qt;                              // slot table: sums to 62 per (i_, nh)
  switch (slot) {
    case 0:  qt = i_;      break;      // 0..7
    case 1:  qt = 15 - i_; break;      // 15..8
    case 2:  qt = 16 + i_; break;      // 16..23
    default: qt = 31 - i_; break;      // 31..24
  }

  int tid = threadIdx.x, wave = tid >> 6, lane = tid & 63;
  int lc = lane & 15, lg = lane >> 4, lg4 = lg * 4;

  __shared__ short QPs[64][72];        // Q then P (wave-local 16-row strips)
  __shared__ short Ks[2][64][72];
  __shared__ float rtab[2048 + 64];    // reversed bias (fp32,*log2e); +64 slack

  for (int ii = tid; ii < 2048; ii += 256) rtab[2047 - ii] = tabF[h * 2048 + ii];

  int sr = tid >> 3, sc = (tid & 7) * 8;           // staging rows sr, sr+32
  const short* kbase0 = qkv + (size_t)(n * 2048) * 3072 + 1024 + h * 64;
  const short* vtbase = vt + (size_t)(n * 1024 + h * 64) * 2048;
  const unsigned long long* mw = mkb + n * 32;
  float* aout = attn_out + (size_t)(n * 16 + h) * 2048 * 2048;

  // stage Q + K0
  const short* qbase = qkv + (size_t)(n * 2048 + qt * 64) * 3072 + h * 64;
  *(s16x8*)&QPs[sr][sc]        = *(const s16x8*)&qbase[(size_t)sr * 3072 + sc];
  *(s16x8*)&QPs[sr + 32][sc]   = *(const s16x8*)&qbase[(size_t)(sr + 32) * 3072 + sc];
  *(s16x8*)&Ks[0][sr][sc]      = *(const s16x8*)&kbase0[(size_t)sr * 3072 + sc];
  *(s16x8*)&Ks[0][sr + 32][sc] = *(const s16x8*)&kbase0[(size_t)(sr + 32) * 3072 + sc];
  __syncthreads();

  s16x8 aq[2];
  #pragma unroll
  for (int ks = 0; ks < 2; ++ks)
    aq[ks] = *(const s16x8*)&QPs[wave * 16 + lc][ks * 32 + lg * 8];
  int qrow = qt * 64 + wave * 16 + lc;
  bool qv = ((mw[qrow >> 6] >> (qrow & 63)) & 1ull) != 0;
  float l = 0.f;

  // ---- pass 1: uniform 32 rounds (compute row sums OR zero-fill) ----------
  for (int kt = 0; kt < 32; ++kt) {
    int cur = kt & 1;
    s16x8 kn0, kn1;
    bool pf = (kt + 1 <= qt);
    if (pf) {
      const short* kb = kbase0 + (size_t)(kt + 1) * 64 * 3072;
      kn0 = *(const s16x8*)&kb[(size_t)sr * 3072 + sc];
      kn1 = *(const s16x8*)&kb[(size_t)(sr + 32) * 3072 + sc];
    }
    if (kt <= qt) {
      int lim = qrow - kt * 64;
      unsigned long long w = mw[kt];
      f32x4 c[4];
      __builtin_amdgcn_s_setprio(1);
      #pragma unroll
      for (int ni = 0; ni < 4; ++ni) {
        c[ni] = (f32x4){0.f, 0.f, 0.f, 0.f};
        #pragma unroll
        for (int ks = 0; ks < 2; ++ks) {
          s16x8 kf = *(const s16x8*)&Ks[cur][ni * 16 + lc][ks * 32 + lg * 8];
          c[ni] = __builtin_amdgcn_mfma_f32_16x16x32_bf16(kf, aq[ks], c[ni], 0, 0, 0);
        }
      }
      __builtin_amdgcn_s_setprio(0);
      if (kt < qt) {                   // interior: no causal compare needed
        #pragma unroll
        for (int ni = 0; ni < 4; ++ni) {
          unsigned nib = (unsigned)(w >> (ni * 16 + lg4));
          int j0 = 2047 - lim + ni * 16 + lg4;
          #pragma unroll
          for (int r = 0; r < 4; ++r) {
            float v = ((nib >> r) & 1u) ? fmaf(c[ni][r], K1, rtab[j0 + r]) : NEGV;
            l += exp2f(v);
          }
        }
      } else {                         // diagonal tile
        #pragma unroll
        for (int ni = 0; ni < 4; ++ni) {
          unsigned nib = (unsigned)(w >> (ni * 16 + lg4));
          int j0 = 2047 - lim + ni * 16 + lg4;
          #pragma unroll
          for (int r = 0; r < 4; ++r) {
            int idx = ni * 16 + lg4 + r;
            bool ok = (((nib >> r) & 1u) != 0) && (idx <= lim);
            float v = ok ? fmaf(c[ni][r], K1, rtab[j0 + r]) : NEGV;
            l += exp2f(v);
          }
        }
      }
    } else {
      // zero-fill this q-tile's k-tile kt (upper triangle), nontemporal
      f32x4 z4 = (f32x4){0.f, 0.f, 0.f, 0.f};
      #pragma unroll
      for (int ii = 0; ii < 4; ++ii) {
        int idx = tid + ii * 256;                  // 0..1023
        int row = idx >> 4, c16 = idx & 15;
        nt_store4(&aout[(size_t)(qt * 64 + row) * 2048 + kt * 64 + c16 * 4], z4);
      }
    }
    if (pf) {
      *(s16x8*)&Ks[cur ^ 1][sr][sc]      = kn0;
      *(s16x8*)&Ks[cur ^ 1][sr + 32][sc] = kn1;
    }
    block_sync_lds();
  }
  l += __shfl_xor(l, 16);
  l += __shfl_xor(l, 32);
  float C_ = qv ? __log2f(l) : 1.0e30f;  // invalid q-row: exp2(v-1e30) = 0

  f32x4 y[4];
  #pragma unroll
  for (int ni = 0; ni < 4; ++ni) y[ni] = (f32x4){0.f, 0.f, 0.f, 0.f};

  // re-stage K0 for pass 2 (prev barrier protects)
  *(s16x8*)&Ks[0][sr][sc]      = *(const s16x8*)&kbase0[(size_t)sr * 3072 + sc];
  *(s16x8*)&Ks[0][sr + 32][sc] = *(const s16x8*)&kbase0[(size_t)(sr + 32) * 3072 + sc];
  block_sync_lds();

  // ---- pass 2: emit normalized attn (nt f32x4) + PV (V direct from L2) ----
  for (int kt = 0; kt <= qt; ++kt) {
    int cur = kt & 1;
    s16x8 kn0, kn1;
    if (kt < qt) {
      const short* kb = kbase0 + (size_t)(kt + 1) * 64 * 3072;
      kn0 = *(const s16x8*)&kb[(size_t)sr * 3072 + sc];
      kn1 = *(const s16x8*)&kb[(size_t)(sr + 32) * 3072 + sc];
    }
    // V frags direct from global (L2-resident); issued early, used post-emit
    const short* vp = vtbase + (size_t)lc * 2048 + kt * 64 + lg * 8;
    s16x8 vf[4][2];
    #pragma unroll
    for (int ni = 0; ni < 4; ++ni) {
      vf[ni][0] = *(const s16x8*)&vp[(size_t)(ni * 16) * 2048];
      vf[ni][1] = *(const s16x8*)&vp[(size_t)(ni * 16) * 2048 + 32];
    }
    unsigned long long w = mw[kt];
    int lim = qrow - kt * 64;
    f32x4 c[4];
    __builtin_amdgcn_s_setprio(1);
    #pragma unroll
    for (int ni = 0; ni < 4; ++ni) {
      c[ni] = (f32x4){0.f, 0.f, 0.f, 0.f};
      #pragma unroll
      for (int ks = 0; ks < 2; ++ks) {
        s16x8 kf = *(const s16x8*)&Ks[cur][ni * 16 + lc][ks * 32 + lg * 8];
        c[ni] = __builtin_amdgcn_mfma_f32_16x16x32_bf16(kf, aq[ks], c[ni], 0, 0, 0);
      }
    }
    __builtin_amdgcn_s_setprio(0);
    #pragma unroll
    for (int ni = 0; ni < 4; ++ni) {
      unsigned nib = (unsigned)(w >> (ni * 16 + lg4));
      int j0 = 2047 - lim + ni * 16 + lg4;
      f32x4 p4;
      if (kt < qt) {
        #pragma unroll
        for (int r = 0; r < 4; ++r) {
          float v = ((nib >> r) & 1u) ? (fmaf(c[ni][r], K1, rtab[j0 + r]) - C_) : -3.0e38f;
          p4[r] = exp2f(v);
        }
      } else {
        #pragma unroll
        for (int r = 0; r < 4; ++r) {
          int idx = ni * 16 + lg4 + r;
          bool ok = (((nib >> r) & 1u) != 0) && (idx <= lim);
          float v = ok ? (fmaf(c[ni][r], K1, rtab[j0 + r]) - C_) : -3.0e38f;
          p4[r] = exp2f(v);
        }
      }
      nt_store4(&aout[(size_t)qrow * 2048 + kt * 64 + ni * 16 + lg4], p4);
      // cheap RNA bf16 pack (values in [0,1])
      unsigned plo = ((__float_as_uint(p4[0]) + 0x8000u) >> 16) |
                     ((__float_as_uint(p4[1]) + 0x8000u) & 0xffff0000u);
      unsigned phi = ((__float_as_uint(p4[2]) + 0x8000u) >> 16) |
                     ((__float_as_uint(p4[3]) + 0x8000u) & 0xffff0000u);
      uint2 pk; pk.x = plo; pk.y = phi;
      *(uint2*)&QPs[wave * 16 + lc][ni * 16 + lg4] = pk;  // wave-local strip
    }
    asm volatile("" ::: "memory");     // forbid hoisting P reads above writes
    __builtin_amdgcn_s_setprio(1);
    #pragma unroll
    for (int ks = 0; ks < 2; ++ks) {
      s16x8 pa = *(const s16x8*)&QPs[wave * 16 + lc][ks * 32 + lg * 8];
      #pragma unroll
      for (int ni = 0; ni < 4; ++ni)
        y[ni] = __builtin_amdgcn_mfma_f32_16x16x32_bf16(pa, vf[ni][ks], y[ni], 0, 0, 0);
    }
    __builtin_amdgcn_s_setprio(0);
    if (kt < qt) {
      *(s16x8*)&Ks[cur ^ 1][sr][sc]      = kn0;
      *(s16x8*)&Ks[cur ^ 1][sr + 32][sc] = kn1;
    }
    block_sync_lds();
  }

  // y store (padded-query rows: p forced 0 -> y 0); y_ws IS re-read -> cached
  #pragma unroll
  for (int ni = 0; ni < 4; ++ni) {
    int col = h * 64 + ni * 16 + lc;
    #pragma unroll
    for (int r = 0; r < 4; ++r) {
      size_t row = (size_t)(n * 2048 + qt * 64 + wave * 16 + lg4 + r);
      y_ws[row * 1024 + col] = f2bf(y[ni][r]);
    }
  }
}

// ---------------------------------------------------------------------------
extern "C" void kernel_launch(void* const* d_in, const int* in_sizes, int n_in,
                              void* d_out, int out_size, void* d_ws, size_t ws_size,
                              hipStream_t stream)
{
  const float* x         = (const float*)d_in[0];
  const int*   mask      = (const int*)d_in[1];
  const float* W_qkv     = (const float*)d_in[4];
  const float* W_out     = (const float*)d_in[5];
  const float* rel_table = (const float*)d_in[6];

  char* ws = (char*)d_ws;
  short*  xb     = (short*)(ws);                 //  8,388,608 B (reused as vt)
  short*  WqkvT  = (short*)(ws + 8388608);       //  6,291,456 B
  short*  WoutT  = (short*)(ws + 14680064);      //  2,097,152 B
  float*  tabF   = (float*)(ws + 16777216);      //    131,072 B
  unsigned long long* mkb = (unsigned long long*)(ws + 16908288); // 512 B
  short*  qkv    = (short*)(ws + 16908800);      // 25,165,824 B
  short*  y_ws   = (short*)(ws + 42074624);      //  8,388,608 B (ends 50,463,232)
  short*  vt     = xb;                           // V^T, written after gemm1 reads xb

  float* y_out    = (float*)d_out;
  float* attn_out = y_out + (size_t)2 * 2048 * 1024;

  prep_all<<<6288, 256, 0, stream>>>(x, xb, W_qkv, WqkvT, W_out, WoutT,
                                     rel_table, tabF, mask, mkb);

  gemm_bt<false><<<dim3(24, 32), 256, 0, stream>>>(xb, WqkvT, (void*)qkv, 4096, 3072, 1024);

  vt_transpose<<<dim3(64, 32, 2), dim3(32, 8), 0, stream>>>(qkv, vt);

  attn_fused<<<1024, 256, 0, stream>>>(qkv, vt, mkb, tabF, attn_out, y_ws);

  gemm_bt64<<<dim3(16, 32), 256, 0, stream>>>(y_ws, WoutT, y_out, 4096, 1024, 1024);
}